// Round 2
// 327.656 us; speedup vs baseline: 1.0594x; 1.0594x over previous
//
#include <hip/hip_runtime.h>
#include <math.h>

// Problem constants (from reference)
#define B_     1024
#define H_     200
#define W_     32
#define COUT_  16
#define TOPK_  50

#define XST 17   // x-tile stride (f32) for the 16 staged columns; odd -> 2-way bank aliasing = free
#define OST 17   // obuf stride (16 + 1 pad)

typedef _Float16 h2 __attribute__((ext_vector_type(2)));
union HU { h2 h; int i; };

// Cross-lane XOR exchange on a 32-bit value.
// DPP (VALU pipe) for j=1,2,8; ds_swizzle for j=4,16; ds_bpermute for j=32.
template<int J>
__device__ __forceinline__ int lane_xor_i(int x) {
    if constexpr (J == 1)  return __builtin_amdgcn_update_dpp(x, x, 0xB1, 0xF, 0xF, true);  // quad_perm [1,0,3,2]
    else if constexpr (J == 2)  return __builtin_amdgcn_update_dpp(x, x, 0x4E, 0xF, 0xF, true);  // quad_perm [2,3,0,1]
    else if constexpr (J == 8)  return __builtin_amdgcn_update_dpp(x, x, 0x128, 0xF, 0xF, true); // row_ror:8 == xor8
    else if constexpr (J == 4)  return __builtin_amdgcn_ds_swizzle(x, 0x101F); // BitMode xor=4
    else if constexpr (J == 16) return __builtin_amdgcn_ds_swizzle(x, 0x401F); // BitMode xor=16
    else { // J == 32 crosses the 32-lane swizzle groups
        int lane = (int)(threadIdx.x & 63);
        return __builtin_amdgcn_ds_bpermute((lane ^ 32) << 2, x);
    }
}

__device__ __forceinline__ int pkmax(int a, int b) {
    HU x, y, r; x.i = a; y.i = b;
    r.h = __builtin_elementwise_max(x.h, y.h);   // v_pk_max_f16
    return r.i;
}
__device__ __forceinline__ int pkmin(int a, int b) {
    HU x, y, r; x.i = a; y.i = b;
    r.h = __builtin_elementwise_min(x.h, y.h);   // v_pk_min_f16
    return r.i;
}

// Packed compare-exchange on int-typed state: exchange + pk_max + pk_min +
// one 32-bit v_cndmask (mask is a hoisted SGPR pair). 4 ops / 2 sequences.
template<int J>
__device__ __forceinline__ void ce2(int& v, bool take_max) {
    int o  = lane_xor_i<J>(v);
    int mx = pkmax(v, o);
    int mn = pkmin(v, o);
    v = take_max ? mx : mn;
}

// Bitonic stage (level J of block K) on chunks 0..2 (asc, desc, asc).
// Uses hoisted bools j<J> = (lane&J)!=0, k<K> = (lane&K)==0.
#define CE4_3(J, K) { const bool tm = (j##J) == (k##K); \
    ce2<J>(v0, tm); ce2<J>(v1, !tm); ce2<J>(v2, tm); }

// Chunk 3: only 8 real values (h=192..199), sort-8 descending.
#define CE3(J, K) { ce2<J>(v3, (j##J) != (k##K)); }

// Applied only at writeout (monotonicity: top-k commutes with tanh).
__device__ __forceinline__ float fast_tanh(float s) {
    // tanh(s) = 1 - 2/(exp(2s)+1)
    float e = __expf(2.0f * s);
    return fmaf(-2.0f, __builtin_amdgcn_rcpf(e + 1.0f), 1.0f);
}

__global__ __launch_bounds__(256, 8) void cnn_topk_kernel(
    const float* __restrict__ x,     // [B,1,H,W]
    const float* __restrict__ cw,    // [COUT,1,3,1]
    const float* __restrict__ cb,    // [COUT]
    float* __restrict__ out)         // [B,COUT,TOPK,W]
{
    __shared__ float xs[(H_ + 2) * XST];   // 13736 B: only this block's 16 columns
    __shared__ int   obuf[TOPK_ * OST];    //  3400 B, per-cp packed results
    // total 17.1 KB -> 8 blocks/CU (thread-capped), was 30.2 KB / 5 blocks

    const int b   = blockIdx.x >> 1;   // batch
    const int wh  = blockIdx.x & 1;    // 16-column half
    const int tid = threadIdx.x;
    const float* xb = x + (size_t)b * (H_ * W_) + wh * 16;

    // ---- stage the 16 needed columns of x[b] -> LDS, zero halo rows ----
    for (int i = tid; i < H_ * 4; i += 256) {       // 4 float4 per row
        int h = i >> 2, q = (i & 3) * 4;
        float4 v = *reinterpret_cast<const float4*>(xb + h * W_ + q);
        float* d = &xs[(h + 1) * XST + q];
        d[0] = v.x; d[1] = v.y; d[2] = v.z; d[3] = v.w;
    }
    if (tid < 16) {
        xs[tid] = 0.0f;
        xs[(H_ + 1) * XST + tid] = 0.0f;
    }
    __syncthreads();

    const int wave = tid >> 6;
    const int lane = tid & 63;

    // Hoisted direction bools (each lives as one 64-bit SGPR-pair mask).
    const bool j1  = (lane & 1)  != 0;
    const bool j2  = (lane & 2)  != 0;
    const bool j4  = (lane & 4)  != 0;
    const bool j8  = (lane & 8)  != 0;
    const bool j16 = (lane & 16) != 0;
    const bool j32 = (lane & 32) != 0;
    const bool k2  = (lane & 2)  == 0;
    const bool k4  = (lane & 4)  == 0;
    const bool k8  = (lane & 8)  == 0;
    const bool k16 = (lane & 16) == 0;
    const bool k32 = (lane & 32) == 0;
    const bool k64 = true;             // (lane & 64) == 0 for lane < 64

    const int SENT = (int)0xFC00FC00;  // packed f16 -inf sentinel (keys are raw conv scores)
    const int h3 = (192 + lane < H_) ? (192 + lane) : (H_ - 1);    // clamped tail row

    for (int cp = 0; cp < 8; ++cp) {
        const int coA = 2 * cp, coB = 2 * cp + 1;
        const float w0A = cw[coA * 3], w1A = cw[coA * 3 + 1], w2A = cw[coA * 3 + 2], bA = cb[coA];
        const float w0B = cw[coB * 3], w1B = cw[coB * 3 + 1], w2B = cw[coB * 3 + 2], bB = cb[coB];

#pragma unroll
        for (int wi = 0; wi < 4; ++wi) {
            const int w = wave * 4 + wi;           // local column 0..15

            // conv only (NO tanh here: tanh is monotone, applied post-selection).
            // Keys = raw conv scores packed to f16 via one v_cvt_pkrtz (monotone).
            int v0, v1, v2, v3;
#define MAKE_V(VR, HROW)                                                     \
            {   const int hh = (HROW);                                       \
                float xm = xs[ hh      * XST + w];                           \
                float xc = xs[(hh + 1) * XST + w];                           \
                float xp = xs[(hh + 2) * XST + w];                           \
                float sA = fmaf(w2A, xp, fmaf(w1A, xc, fmaf(w0A, xm, bA)));  \
                float sB = fmaf(w2B, xp, fmaf(w1B, xc, fmaf(w0B, xm, bB)));  \
                VR = __builtin_bit_cast(int, __builtin_amdgcn_cvt_pkrtz(sA, sB)); }
            MAKE_V(v0, lane)
            MAKE_V(v1, 64 + lane)
            MAKE_V(v2, 128 + lane)
            MAKE_V(v3, h3)
#undef MAKE_V
            v3 = (lane < 8) ? v3 : SENT;   // tail chunk: 8 real values

            // ---- sort chunks 0..2 (asc, desc, asc), 21 stages ----
            CE4_3(1, 2)
            CE4_3(2, 4)  CE4_3(1, 4)
            CE4_3(4, 8)  CE4_3(2, 8)  CE4_3(1, 8)
            CE4_3(8, 16) CE4_3(4, 16) CE4_3(2, 16) CE4_3(1, 16)
            CE4_3(16,32) CE4_3(8, 32) CE4_3(4, 32) CE4_3(2, 32) CE4_3(1, 32)
            CE4_3(32,64) CE4_3(16,64) CE4_3(8, 64) CE4_3(4, 64) CE4_3(2, 64) CE4_3(1, 64)

            // ---- chunk 3: sort-8 descending ----
            CE3(1, 2)
            CE3(2, 4)  CE3(1, 4)
            CE3(4, 8)  CE3(2, 8)  CE3(1, 8)

            // ---- top-64 merges ----
            int m1 = pkmax(v0, v1);     // bitonic
            int m2 = pkmax(v2, v3);     // bitonic
#define MM(J) { ce2<J>(m1, j##J); ce2<J>(m2, !(j##J)); }
            MM(32) MM(16) MM(8) MM(4) MM(2) MM(1)
#undef MM
            int t = pkmax(m1, m2);      // top-64 of 256, bitonic
#define MT(J) { ce2<J>(t, !(j##J)); }
            MT(32) MT(16) MT(8) MT(4) MT(2) MT(1)
#undef MT

            if (lane < TOPK_) obuf[lane * OST + w] = t;
        }
        __syncthreads();   // all 16 w of this cp in obuf

        // ---- coalesced write-out for this co-pair (800 entries) ----
        // tanh applied HERE only: 50 per lane total vs 256 in the old loop.
#pragma unroll
        for (int j = 0; j < 4; ++j) {
            int idx = tid + j * 256;
            if (idx < 800) {
                int k = idx >> 4, w2 = idx & 15;
                HU u; u.i = obuf[k * OST + w2];
                size_t o0 = (((size_t)b * COUT_ + coA) * TOPK_ + k) * W_ + wh * 16 + w2;
                out[o0]                        = fast_tanh((float)u.h.x);
                out[o0 + (size_t)TOPK_ * W_]   = fast_tanh((float)u.h.y);
            }
        }
        __syncthreads();   // obuf free for next cp
    }
}

extern "C" void kernel_launch(void* const* d_in, const int* in_sizes, int n_in,
                              void* d_out, int out_size, void* d_ws, size_t ws_size,
                              hipStream_t stream) {
    const float* x  = (const float*)d_in[0];   // [1024,1,200,32]
    const float* cw = (const float*)d_in[1];   // [16,1,3,1]
    const float* cb = (const float*)d_in[2];   // [16]
    float* out = (float*)d_out;                // [1024,16,50,32]

    cnn_topk_kernel<<<dim3(B_ * 2), dim3(256), 0, stream>>>(x, cw, cb, out);
}

// Round 3
// 303.545 us; speedup vs baseline: 1.1436x; 1.0794x over previous
//
#include <hip/hip_runtime.h>
#include <math.h>

// Problem constants (from reference)
#define B_     1024
#define H_     200
#define W_     32
#define COUT_  16
#define TOPK_  50

#define XST 17   // x-tile stride (f32) for the 16 staged columns; odd -> 2-way bank aliasing = free
#define OST 17   // obuf stride (16 + 1 pad)

typedef _Float16 h2 __attribute__((ext_vector_type(2)));
union HU { h2 h; int i; };

// Compile-time 64-bit lane mask for bitonic stage (J = exchange distance,
// K = block size). take_max(lane) = bit_J(lane) XOR bit_K(lane); K=64 -> bit_J.
constexpr unsigned long long lane_mask(int J, int K) {
    unsigned long long m = 0;
    for (int l = 0; l < 64; ++l) {
        bool a = (l & J) != 0;
        bool b = (K < 64) && ((l & K) != 0);
        if (a != b) m |= (1ull << l);
    }
    return m;
}

// Cross-lane XOR exchange on a 32-bit value.
// DPP (VALU pipe) for j=1,2,8; ds_swizzle for j=4,16; ds_bpermute for j=32.
template<int J>
__device__ __forceinline__ int lane_xor_i(int x) {
    if constexpr (J == 1)  return __builtin_amdgcn_update_dpp(x, x, 0xB1, 0xF, 0xF, true);  // quad_perm [1,0,3,2]
    else if constexpr (J == 2)  return __builtin_amdgcn_update_dpp(x, x, 0x4E, 0xF, 0xF, true);  // quad_perm [2,3,0,1]
    else if constexpr (J == 8)  return __builtin_amdgcn_update_dpp(x, x, 0x128, 0xF, 0xF, true); // row_ror:8 == xor8
    else if constexpr (J == 4)  return __builtin_amdgcn_ds_swizzle(x, 0x101F); // BitMode xor=4
    else if constexpr (J == 16) return __builtin_amdgcn_ds_swizzle(x, 0x401F); // BitMode xor=16
    else { // J == 32 crosses the 32-lane swizzle groups
        int lane = (int)(threadIdx.x & 63);
        return __builtin_amdgcn_ds_bpermute((lane ^ 32) << 2, x);
    }
}

// Guaranteed 4-op packed compare-exchange: exchange + v_pk_max_f16 +
// v_pk_min_f16 + v_cndmask_b32 with an SGPR-pair constant mask.
template<int J>
__device__ __forceinline__ void ce2m(int& v, unsigned long long mask) {
    int o = lane_xor_i<J>(v);
    int mx, mn;
    asm("v_pk_max_f16 %0, %1, %2" : "=v"(mx) : "v"(v), "v"(o));
    asm("v_pk_min_f16 %0, %1, %2" : "=v"(mn) : "v"(v), "v"(o));
    asm("v_cndmask_b32 %0, %1, %2, %3" : "=v"(v) : "v"(mn), "v"(mx), "s"(mask));
}

// Plain packed max (for the merge steps).
__device__ __forceinline__ int pkmax(int a, int b) {
    int r;
    asm("v_pk_max_f16 %0, %1, %2" : "=v"(r) : "v"(a), "v"(b));
    return r;
}

// Bitonic stage (level J of block K) on chunks 0..2 (asc, desc, asc).
#define CE4_3(J, K) { constexpr unsigned long long M = lane_mask(J, K); \
    ce2m<J>(v0, M); ce2m<J>(v1, ~M); ce2m<J>(v2, M); }

// Chunk 3: only 8 real values (h=192..199), sort-8 descending.
#define CE3(J, K) { constexpr unsigned long long M = ~lane_mask(J, K); ce2m<J>(v3, M); }

// Applied only at writeout (monotonicity: top-k commutes with tanh).
__device__ __forceinline__ float fast_tanh(float s) {
    // tanh(s) = 1 - 2/(exp(2s)+1)
    float e = __expf(2.0f * s);
    return fmaf(-2.0f, __builtin_amdgcn_rcpf(e + 1.0f), 1.0f);
}

__global__ __launch_bounds__(256, 8) void cnn_topk_kernel(
    const float* __restrict__ x,     // [B,1,H,W]
    const float* __restrict__ cw,    // [COUT,1,3,1]
    const float* __restrict__ cb,    // [COUT]
    float* __restrict__ out)         // [B,COUT,TOPK,W]
{
    __shared__ float xs[(H_ + 2) * XST];   // 13736 B: only this block's 16 columns
    __shared__ int   obuf[TOPK_ * OST];    //  3400 B, per-cp packed results
    // total 17.1 KB -> 8 blocks/CU (thread-capped)

    const int b   = blockIdx.x >> 1;   // batch
    const int wh  = blockIdx.x & 1;    // 16-column half
    const int tid = threadIdx.x;
    const float* xb = x + (size_t)b * (H_ * W_) + wh * 16;

    // ---- stage the 16 needed columns of x[b] -> LDS, zero halo rows ----
    for (int i = tid; i < H_ * 4; i += 256) {       // 4 float4 per row
        int h = i >> 2, q = (i & 3) * 4;
        float4 v = *reinterpret_cast<const float4*>(xb + h * W_ + q);
        float* d = &xs[(h + 1) * XST + q];
        d[0] = v.x; d[1] = v.y; d[2] = v.z; d[3] = v.w;
    }
    if (tid < 16) {
        xs[tid] = 0.0f;
        xs[(H_ + 1) * XST + tid] = 0.0f;
    }
    __syncthreads();

    const int wave = tid >> 6;
    const int lane = tid & 63;

    const int SENT = (int)0xFC00FC00;  // packed f16 -inf sentinel (keys are raw conv scores)
    const int h3 = (192 + lane < H_) ? (192 + lane) : (H_ - 1);    // clamped tail row

    for (int cp = 0; cp < 8; ++cp) {
        const int coA = 2 * cp, coB = 2 * cp + 1;
        const float w0A = cw[coA * 3], w1A = cw[coA * 3 + 1], w2A = cw[coA * 3 + 2], bA = cb[coA];
        const float w0B = cw[coB * 3], w1B = cw[coB * 3 + 1], w2B = cw[coB * 3 + 2], bB = cb[coB];

#pragma unroll
        for (int wi = 0; wi < 4; ++wi) {
            const int w = wave * 4 + wi;           // local column 0..15

            // conv only (NO tanh here: tanh is monotone, applied post-selection).
            // Keys = raw conv scores packed to f16 via one v_cvt_pkrtz (monotone).
            int v0, v1, v2, v3;
#define MAKE_V(VR, HROW)                                                     \
            {   const int hh = (HROW);                                       \
                float xm = xs[ hh      * XST + w];                           \
                float xc = xs[(hh + 1) * XST + w];                           \
                float xp = xs[(hh + 2) * XST + w];                           \
                float sA = fmaf(w2A, xp, fmaf(w1A, xc, fmaf(w0A, xm, bA)));  \
                float sB = fmaf(w2B, xp, fmaf(w1B, xc, fmaf(w0B, xm, bB)));  \
                VR = __builtin_bit_cast(int, __builtin_amdgcn_cvt_pkrtz(sA, sB)); }
            MAKE_V(v0, lane)
            MAKE_V(v1, 64 + lane)
            MAKE_V(v2, 128 + lane)
            MAKE_V(v3, h3)
#undef MAKE_V
            v3 = (lane < 8) ? v3 : SENT;   // tail chunk: 8 real values

            // ---- sort chunks 0..2 (asc, desc, asc), 21 stages ----
            CE4_3(1, 2)
            CE4_3(2, 4)  CE4_3(1, 4)
            CE4_3(4, 8)  CE4_3(2, 8)  CE4_3(1, 8)
            CE4_3(8, 16) CE4_3(4, 16) CE4_3(2, 16) CE4_3(1, 16)
            CE4_3(16,32) CE4_3(8, 32) CE4_3(4, 32) CE4_3(2, 32) CE4_3(1, 32)
            CE4_3(32,64) CE4_3(16,64) CE4_3(8, 64) CE4_3(4, 64) CE4_3(2, 64) CE4_3(1, 64)

            // ---- chunk 3: sort-8 descending ----
            CE3(1, 2)
            CE3(2, 4)  CE3(1, 4)
            CE3(4, 8)  CE3(2, 8)  CE3(1, 8)

            // ---- top-64 merges ----
            int m1 = pkmax(v0, v1);     // bitonic
            int m2 = pkmax(v2, v3);     // bitonic
#define MM(J) { constexpr unsigned long long M = lane_mask(J, 64); \
                ce2m<J>(m1, M); ce2m<J>(m2, ~M); }
            MM(32) MM(16) MM(8) MM(4) MM(2) MM(1)
#undef MM
            int t = pkmax(m1, m2);      // top-64 of 256, bitonic
#define MT(J) { constexpr unsigned long long M = ~lane_mask(J, 64); ce2m<J>(t, M); }
            MT(32) MT(16) MT(8) MT(4) MT(2) MT(1)
#undef MT

            if (lane < TOPK_) obuf[lane * OST + w] = t;
        }
        __syncthreads();   // all 16 w of this cp in obuf

        // ---- coalesced write-out for this co-pair (800 entries) ----
        // tanh applied HERE only: 50 per lane total vs 256 in the old loop.
#pragma unroll
        for (int j = 0; j < 4; ++j) {
            int idx = tid + j * 256;
            if (idx < 800) {
                int k = idx >> 4, w2 = idx & 15;
                HU u; u.i = obuf[k * OST + w2];
                size_t o0 = (((size_t)b * COUT_ + coA) * TOPK_ + k) * W_ + wh * 16 + w2;
                out[o0]                        = fast_tanh((float)u.h.x);
                out[o0 + (size_t)TOPK_ * W_]   = fast_tanh((float)u.h.y);
            }
        }
        __syncthreads();   // obuf free for next cp
    }
}

extern "C" void kernel_launch(void* const* d_in, const int* in_sizes, int n_in,
                              void* d_out, int out_size, void* d_ws, size_t ws_size,
                              hipStream_t stream) {
    const float* x  = (const float*)d_in[0];   // [1024,1,200,32]
    const float* cw = (const float*)d_in[1];   // [16,1,3,1]
    const float* cb = (const float*)d_in[2];   // [16]
    float* out = (float*)d_out;                // [1024,16,50,32]

    cnn_topk_kernel<<<dim3(B_ * 2), dim3(256), 0, stream>>>(x, cw, cb, out);
}